// Round 2
// baseline (805.275 us; speedup 1.0000x reference)
//
#include <hip/hip_runtime.h>
#include <hip/hip_bf16.h>

// Steerable pyramid via hand-written Stockham LDS FFTs.
// Layouts: spectra stored as (image, row u, col v) float2, W = H/2+1.
// fftshift folded into filter indexing: filt[(u + H/2) & (H-1)].

#define PI_F 3.14159265358979323846f

// In-LDS Stockham radix-2 FFT. F interleaved FFTs of length N, layout buf[f*N + p].
// 256 threads. Returns pointer to result buffer. INV => e^{+i...}, unnormalized.
template<int N, int F, bool INV>
__device__ inline float2* fft_lds(float2* bufa, float2* bufb, int tid) {
    constexpr int HB = N / 2;
    constexpr int NB = F * HB;
    float2* src = bufa;
    float2* dst = bufb;
#pragma unroll
    for (int Ns = 1; Ns < N; Ns <<= 1) {
        __syncthreads();
#pragma unroll
        for (int qq = 0; qq < NB; qq += 256) {
            int q = qq + tid;
            int f = q / HB;
            int j = q % HB;
            float2 u = src[f * N + j];
            float2 v = src[f * N + j + HB];
            int r = j & (Ns - 1);
            float ang = (INV ? PI_F : -PI_F) * (float)r / (float)Ns;
            float s, c;
            __sincosf(ang, &s, &c);
            float2 w = make_float2(v.x * c - v.y * s, v.x * s + v.y * c);
            int d = ((j - r) << 1) | r;  // (j/Ns)*2Ns + r
            dst[f * N + d]      = make_float2(u.x + w.x, u.y + w.y);
            dst[f * N + d + Ns] = make_float2(u.x - w.x, u.y - w.y);
        }
        float2* t = src; src = dst; dst = t;
    }
    __syncthreads();
    return src;
}

// Forward row rfft: two real rows packed into one complex FFT-512.
__global__ __launch_bounds__(256) void k_fwd_rows(const float* __restrict__ x,
                                                  float2* __restrict__ S) {
    __shared__ float2 lds[2][512];
    int bid = blockIdx.x;
    int i = bid >> 8;       // image 0..23
    int p = bid & 255;      // row pair
    int yA = 2 * p;
    const float* rA = x + ((size_t)(i * 512 + yA)) * 512;
    int tid = threadIdx.x;
    for (int t = tid; t < 512; t += 256)
        lds[0][t] = make_float2(rA[t], rA[512 + t]);
    float2* res = fft_lds<512, 1, false>(&lds[0][0], &lds[1][0], tid);
    float2* SA = S + ((size_t)(i * 512 + yA)) * 257;
    float2* SB = SA + 257;
    for (int v = tid; v < 257; v += 256) {
        float2 Zv = res[v];
        float2 Zc = res[(512 - v) & 511];
        SA[v] = make_float2(0.5f * (Zv.x + Zc.x), 0.5f * (Zv.y - Zc.y));
        SB[v] = make_float2(0.5f * (Zv.y + Zc.y), 0.5f * (Zc.x - Zv.x));
    }
}

// Forward column FFT, in place on S. CB columns per block.
template<int N, int CB>
__global__ __launch_bounds__(256) void k_fwd_cols(float2* __restrict__ S, int W, int nTiles) {
    __shared__ float2 lds[2][CB * N];
    int tid = threadIdx.x, bid = blockIdx.x;
    int i = bid / nTiles;
    int v0 = (bid % nTiles) * CB;
    float2* base = S + (size_t)i * N * W;
    for (int q = tid; q < CB * N; q += 256) {
        int c = q % CB, r = q / CB, v = v0 + c;
        lds[0][c * N + r] = (v < W) ? base[(size_t)r * W + v] : make_float2(0.f, 0.f);
    }
    float2* res = fft_lds<N, CB, false>(&lds[0][0], &lds[1][0], tid);
    for (int q = tid; q < CB * N; q += 256) {
        int c = q % CB, r = q / CB, v = v0 + c;
        if (v < W) base[(size_t)r * W + v] = res[c * N + r];
    }
}

// LF0 = hl0[1] * S (pointwise, shifted row indexing)
__global__ void k_lf0(const float2* __restrict__ S, const float* __restrict__ hl0,
                      float2* __restrict__ LF0) {
    int idx = blockIdx.x * 256 + threadIdx.x;
    if (idx >= 24 * 512 * 257) return;
    int rem = idx % (512 * 257);
    int u = rem / 257, v = rem % 257;
    float f = hl0[512 * 257 + (((u + 256) & 511) * 257 + v)];
    float2 s = S[idx];
    LF0[idx] = make_float2(s.x * f, s.y * f);
}

// Crop + lowpass multiply: LF at size H -> size H/2.
template<int H>
__global__ void k_crop(const float2* __restrict__ LFn, const float* __restrict__ ls,
                       float2* __restrict__ LFo) {
    constexpr int H2 = H / 2, W2 = H2 / 2 + 1, W = H / 2 + 1;
    int idx = blockIdx.x * 256 + threadIdx.x;
    if (idx >= 24 * H2 * W2) return;
    int i = idx / (H2 * W2);
    int rem = idx % (H2 * W2);
    int u2 = rem / W2, v = rem % W2;
    int s2 = (u2 + H2 / 2) & (H2 - 1);
    int uo = (3 * (H / 4) + s2) & (H - 1);
    float f = ls[s2 * W2 + v];
    float2 t = LFn[((size_t)i * H + uo) * W + v];
    LFo[idx] = make_float2(t.x * f, t.y * f);
}

// Inverse column FFT with on-the-fly filter multiply. Writes Z (i,u,v).
template<int N, int CB, bool HASF>
__global__ __launch_bounds__(256) void k_inv_cols(const float2* __restrict__ spec,
                                                  const float* __restrict__ filt,
                                                  float2* __restrict__ Z, int nTiles) {
    constexpr int W = N / 2 + 1;
    __shared__ float2 lds[2][CB * N];
    int tid = threadIdx.x, bid = blockIdx.x;
    int i = bid / nTiles;
    int v0 = (bid % nTiles) * CB;
    const float2* base = spec + (size_t)i * N * W;
    for (int q = tid; q < CB * N; q += 256) {
        int c = q % CB, r = q / CB, v = v0 + c;
        float2 val = make_float2(0.f, 0.f);
        if (v < W) {
            val = base[(size_t)r * W + v];
            if (HASF) {
                float f = filt[((r + N / 2) & (N - 1)) * W + v];
                val.x *= f; val.y *= f;
            }
        }
        lds[0][c * N + r] = val;
    }
    float2* res = fft_lds<N, CB, true>(&lds[0][0], &lds[1][0], tid);
    for (int q = tid; q < CB * N; q += 256) {
        int c = q % CB, r = q / CB, v = v0 + c;
        if (v < W) Z[((size_t)i * N + r) * W + v] = res[c * N + r];
    }
}

// Row-wise irfft (numpy semantics: imag of DC & Nyquist dropped), scale 1/N^2.
template<int N, int RB>
__global__ __launch_bounds__(256) void k_irfft_rows(const float2* __restrict__ Z,
                                                    float* __restrict__ outB,
                                                    int CH, int ch, int rowBlocks) {
    constexpr int W = N / 2 + 1;
    __shared__ float2 lds[2][RB * N];
    int tid = threadIdx.x, bid = blockIdx.x;
    int i = bid / rowBlocks;
    int u0 = (bid % rowBlocks) * RB;
    for (int q = tid; q < RB * N; q += 256) {
        int f = q / N, p = q % N;
        const float2* Zr = Z + ((size_t)i * N + (u0 + f)) * W;
        float2 val;
        if (p == 0)            { float2 t = Zr[0];     val = make_float2(t.x, 0.f); }
        else if (p < N / 2)    { val = Zr[p]; }
        else if (p == N / 2)   { float2 t = Zr[N / 2]; val = make_float2(t.x, 0.f); }
        else                   { float2 t = Zr[N - p]; val = make_float2(t.x, -t.y); }
        lds[0][f * N + p] = val;
    }
    float2* res = fft_lds<N, RB, true>(&lds[0][0], &lds[1][0], tid);
    constexpr float sc = 1.0f / ((float)N * (float)N);
    for (int q = tid; q < RB * N; q += 256) {
        int f = q / N, p = q % N;
        int u = u0 + f;
        outB[(((size_t)i * CH + ch) * N + u) * N + p] = res[f * N + p].x * sc;
    }
}

extern "C" void kernel_launch(void* const* d_in, const int* in_sizes, int n_in,
                              void* d_out, int out_size, void* d_ws, size_t ws_size,
                              hipStream_t stream) {
    // Map inputs by element count (all distinct) — immune to dict-order surprises.
    auto find = [&](int sz) -> const float* {
        for (int t = 0; t < n_in; ++t)
            if (in_sizes[t] == sz) return (const float*)d_in[t];
        return nullptr;
    };
    const float* x   = find(6291456);   // (8,3,512,512)
    const float* hl0 = find(263168);    // (2,512,257)
    const float* b0f = find(526336);    // (4,512,257)
    const float* l0f = find(33024);     // (1,256,129)
    const float* b1f = find(132096);    // (4,256,129)
    const float* l1f = find(8320);      // (1,128,65)
    const float* b2f = find(33280);     // (4,128,65)
    const float* l2f = find(2112);      // (1,64,33)
    const float* b3f = find(8448);      // (4,64,33)
    const float* l3f = find(544);       // (1,32,17)
    float* out = (float*)d_out;
    if (!x || !hl0 || !b0f || !l0f || !b1f || !l1f || !b2f || !l2f || !b3f || !l3f) return;

    char* w = (char*)d_ws;
    float2* S   = (float2*)w; w += (size_t)24 * 512 * 257 * 8;
    float2* LF0 = (float2*)w; w += (size_t)24 * 512 * 257 * 8;
    float2* LF1 = (float2*)w; w += (size_t)24 * 256 * 129 * 8;
    float2* LF2 = (float2*)w; w += (size_t)24 * 128 * 65 * 8;
    float2* LF3 = (float2*)w; w += (size_t)24 * 64 * 33 * 8;
    float2* LF4 = (float2*)w; w += (size_t)24 * 32 * 17 * 8;
    float2* Z   = (float2*)w; w += (size_t)24 * 512 * 257 * 8;
    if ((size_t)(w - (char*)d_ws) > ws_size) return;  // need ~84.3 MB

    // Forward rfft2
    k_fwd_rows<<<24 * 256, 256, 0, stream>>>(x, S);
    k_fwd_cols<512, 4><<<24 * 65, 256, 0, stream>>>(S, 257, 65);

    // Lowpass chain
    { int n = 24 * 512 * 257; k_lf0<<<(n + 255) / 256, 256, 0, stream>>>(S, hl0, LF0); }
    { int n = 24 * 256 * 129; k_crop<512><<<(n + 255) / 256, 256, 0, stream>>>(LF0, l0f, LF1); }
    { int n = 24 * 128 * 65;  k_crop<256><<<(n + 255) / 256, 256, 0, stream>>>(LF1, l1f, LF2); }
    { int n = 24 * 64 * 33;   k_crop<128><<<(n + 255) / 256, 256, 0, stream>>>(LF2, l2f, LF3); }
    { int n = 24 * 32 * 17;   k_crop<64><<<(n + 255) / 256, 256, 0, stream>>>(LF3, l3f, LF4); }

    // h0 (out0): hl0 channel 0 on S
    k_inv_cols<512, 4, true><<<24 * 65, 256, 0, stream>>>(S, hl0, Z, 65);
    k_irfft_rows<512, 4><<<24 * 128, 256, 0, stream>>>(Z, out + 0, 1, 0, 128);

    // b0 (out1): 4 orientations on LF0
    for (int k = 0; k < 4; ++k) {
        k_inv_cols<512, 4, true><<<24 * 65, 256, 0, stream>>>(LF0, b0f + (size_t)k * 512 * 257, Z, 65);
        k_irfft_rows<512, 4><<<24 * 128, 256, 0, stream>>>(Z, out + 6291456, 4, k, 128);
    }
    // b1 (out2)
    for (int k = 0; k < 4; ++k) {
        k_inv_cols<256, 8, true><<<24 * 17, 256, 0, stream>>>(LF1, b1f + (size_t)k * 256 * 129, Z, 17);
        k_irfft_rows<256, 8><<<24 * 32, 256, 0, stream>>>(Z, out + 31457280, 4, k, 32);
    }
    // b2 (out3)
    for (int k = 0; k < 4; ++k) {
        k_inv_cols<128, 16, true><<<24 * 5, 256, 0, stream>>>(LF2, b2f + (size_t)k * 128 * 65, Z, 5);
        k_irfft_rows<128, 16><<<24 * 8, 256, 0, stream>>>(Z, out + 37748736, 4, k, 8);
    }
    // b3 (out4)
    for (int k = 0; k < 4; ++k) {
        k_inv_cols<64, 32, true><<<24 * 2, 256, 0, stream>>>(LF3, b3f + (size_t)k * 64 * 33, Z, 2);
        k_irfft_rows<64, 32><<<24 * 2, 256, 0, stream>>>(Z, out + 39321600, 4, k, 2);
    }
    // final lowpass (out5)
    k_inv_cols<32, 64, false><<<24 * 1, 256, 0, stream>>>(LF4, nullptr, Z, 1);
    k_irfft_rows<32, 32><<<24 * 1, 256, 0, stream>>>(Z, out + 39714816, 1, 0, 1);

    (void)out_size; (void)ws_size;
}

// Round 4
// 605.848 us; speedup vs baseline: 1.3292x; 1.3292x over previous
//
#include <hip/hip_runtime.h>
#include <hip/hip_bf16.h>

// Steerable pyramid via mixed radix-4/radix-2 Stockham LDS FFTs + twiddle tables.
// Spectra layout: (image, row u, col v) float2, W = H/2+1.
// fftshift folded into filter indexing: filt[(u + H/2) & (H-1)].

#define PI_F 3.14159265358979323846f

static __device__ inline float2 f2add(float2 a, float2 b){ return make_float2(a.x+b.x, a.y+b.y); }
static __device__ inline float2 f2sub(float2 a, float2 b){ return make_float2(a.x-b.x, a.y-b.y); }
static __device__ inline float2 cmul(float2 a, float2 b){ return make_float2(a.x*b.x - a.y*b.y, a.x*b.y + a.y*b.x); }

// tw[m] = exp(sign * 2*pi*i * m / N), sign = +1 if INV
template<int N, bool INV>
static __device__ inline void fill_tw(float2* tw, int tid) {
    for (int m = tid; m < N; m += 256) {
        float ang = (INV ? 2.0f * PI_F : -2.0f * PI_F) * (float)m / (float)N;
        float s, c; __sincosf(ang, &s, &c);
        tw[m] = make_float2(c, s);
    }
}

// Mixed-radix Stockham (DIT, autosort). F interleaved FFTs of length N, buf[f*N + p].
// 256 threads; requires F*N/4 to be a multiple of 256 (and F*N/2 for odd log2).
template<int N, int F, bool INV>
static __device__ float2* fft_lds(float2* bufa, float2* bufb, const float2* tw, int tid) {
    constexpr int L = (N==512)?9:(N==256)?8:(N==128)?7:(N==64)?6:5;
    float2* src = bufa;
    float2* dst = bufb;
    if constexpr (L & 1) {   // radix-2 first stage, Ns=1: w == 1
        __syncthreads();
        constexpr int NB = F * (N/2);
#pragma unroll
        for (int qq = 0; qq < NB; qq += 256) {
            int q = qq + tid;
            int f = q / (N/2), j = q % (N/2);
            float2 u = src[f*N + j];
            float2 v = src[f*N + j + N/2];
            dst[f*N + 2*j]     = f2add(u, v);
            dst[f*N + 2*j + 1] = f2sub(u, v);
        }
        float2* t = src; src = dst; dst = t;
    }
    constexpr int S4 = L / 2;           // number of radix-4 stages
    constexpr int NB4 = F * (N/4);
#pragma unroll
    for (int s = 0; s < S4; ++s) {
        const int Ns = ((L & 1) ? 2 : 1) << (2*s);
        __syncthreads();
#pragma unroll
        for (int qq = 0; qq < NB4; qq += 256) {
            int q = qq + tid;
            int f = q / (N/4), j = q % (N/4);
            int r = j & (Ns - 1);
            int m = r * (N / (4*Ns));   // w_k = tw[k*m]
            float2 w1 = tw[m];
            float2 w2 = tw[(2*m) & (N-1)];
            float2 w3 = tw[(3*m) & (N-1)];
            const float2* sp = src + f*N + j;
            float2 c0 = sp[0];
            float2 c1 = cmul(w1, sp[N/4]);
            float2 c2 = cmul(w2, sp[2*(N/4)]);
            float2 c3 = cmul(w3, sp[3*(N/4)]);
            float2 t0 = f2add(c0, c2), t1 = f2sub(c0, c2);
            float2 t2 = f2add(c1, c3), d  = f2sub(c1, c3);
            float2 t3 = INV ? make_float2(-d.y, d.x) : make_float2(d.y, -d.x);
            float2* dp = dst + f*N + (((j - r) << 2) | r);
            dp[0]      = f2add(t0, t2);
            dp[Ns]     = f2add(t1, t3);
            dp[2*Ns]   = f2sub(t0, t2);
            dp[3*Ns]   = f2sub(t1, t3);
        }
        float2* t = src; src = dst; dst = t;
    }
    __syncthreads();
    return src;
}

// Forward row rfft: 2 FFTs per block, each packing two real rows (4 rows/block).
__global__ __launch_bounds__(256) void k_fwd_rows(const float* __restrict__ x,
                                                  float2* __restrict__ S) {
    __shared__ float2 lds[2][2*512];
    __shared__ float2 tw[512];
    int bid = blockIdx.x;
    int i = bid / 128, p = bid % 128;
    int y0 = 4 * p;
    const float* rbase = x + ((size_t)(i*512 + y0)) * 512;
    int tid = threadIdx.x;
    fill_tw<512,false>(tw, tid);
    for (int t = tid; t < 1024; t += 256) {
        int f = t / 512, idx = t % 512;
        lds[0][f*512 + idx] = make_float2(rbase[(size_t)(2*f)*512 + idx],
                                          rbase[(size_t)(2*f+1)*512 + idx]);
    }
    float2* res = fft_lds<512,2,false>(&lds[0][0], &lds[1][0], tw, tid);
    for (int t = tid; t < 2*257; t += 256) {
        int f = t / 257, v = t % 257;
        float2 Zv = res[f*512 + v];
        float2 Zc = res[f*512 + ((512 - v) & 511)];
        float2* SA = S + ((size_t)(i*512 + y0 + 2*f)) * 257;
        SA[v]       = make_float2(0.5f*(Zv.x + Zc.x), 0.5f*(Zv.y - Zc.y));
        SA[257 + v] = make_float2(0.5f*(Zv.y + Zc.y), 0.5f*(Zc.x - Zv.x));
    }
}

// Forward column FFT, in place on S.
template<int N, int CB>
__global__ __launch_bounds__(256) void k_fwd_cols(float2* __restrict__ S, int nTiles) {
    constexpr int W = N/2 + 1;
    __shared__ float2 lds[2][CB*N];
    __shared__ float2 tw[N];
    int tid = threadIdx.x, bid = blockIdx.x;
    int i = bid / nTiles, v0 = (bid % nTiles) * CB;
    fill_tw<N,false>(tw, tid);
    float2* base = S + (size_t)i * N * W;
    for (int q = tid; q < CB*N; q += 256) {
        int c = q % CB, r = q / CB, v = v0 + c;
        lds[0][c*N + r] = (v < W) ? base[(size_t)r*W + v] : make_float2(0.f, 0.f);
    }
    float2* res = fft_lds<N, CB, false>(&lds[0][0], &lds[1][0], tw, tid);
    for (int q = tid; q < CB*N; q += 256) {
        int c = q % CB, r = q / CB, v = v0 + c;
        if (v < W) base[(size_t)r*W + v] = res[c*N + r];
    }
}

// Compute LF1..LF4 directly from S: composed crop-gathers x product of filter taps.
__global__ void k_lfall(const float2* __restrict__ S, const float* __restrict__ hl0,
                        const float* __restrict__ l0, const float* __restrict__ l1,
                        const float* __restrict__ l2, const float* __restrict__ l3,
                        float2* __restrict__ LF1, float2* __restrict__ LF2,
                        float2* __restrict__ LF3, float2* __restrict__ LF4) {
    const int P1 = 256*129, P2 = 128*65, P3 = 64*33, P4 = 32*17;
    const int T1 = 24*P1, T2 = 24*P2, T3 = 24*P3, T4 = 24*P4;
    int idx = blockIdx.x * 256 + threadIdx.x;
    int lev, rem, perim; float2* dst;
    if (idx < T1)                { lev = 1; rem = idx;              perim = P1; dst = LF1; }
    else if (idx < T1+T2)        { lev = 2; rem = idx - T1;        perim = P2; dst = LF2; }
    else if (idx < T1+T2+T3)     { lev = 3; rem = idx - T1 - T2;   perim = P3; dst = LF3; }
    else if (idx < T1+T2+T3+T4)  { lev = 4; rem = idx - T1-T2-T3;  perim = P4; dst = LF4; }
    else return;
    int i = rem / perim;
    int off = rem % perim;
    int Hn = 512 >> lev, Wn = Hn/2 + 1;
    int u = off / Wn, v = off % Wn;
    float f = 1.0f;
    for (int m = lev - 1; m >= 0; --m) {
        int Hc = 512 >> (m + 1);          // child (finer-crop) size
        int Wc = Hc/2 + 1;
        int s2 = (u + Hc/2) & (Hc - 1);
        const float* ls = (m==0) ? l0 : (m==1) ? l1 : (m==2) ? l2 : l3;
        f *= ls[s2 * Wc + v];
        int Hp = 512 >> m;                // parent size
        u = (3*(Hp/4) + s2) & (Hp - 1);
    }
    f *= hl0[512*257 + (((u + 256) & 511) * 257 + v)];
    float2 sv = S[((size_t)i * 512 + u) * 257 + v];
    dst[(size_t)i * perim + off] = make_float2(sv.x * f, sv.y * f);
}

// Inverse column FFT with filter multiply; gridDim.y selects spectrum/orientation.
// MODE: 0 = no filter; 1 = single filter; 2 = y>=1 additionally multiplies filtH.
template<int N, int CB, int MODE>
__global__ __launch_bounds__(256) void k_inv_cols(
        const float2* __restrict__ specA, const float2* __restrict__ specB,
        const float* __restrict__ filtA, const float* __restrict__ filtB, int filtStride,
        const float* __restrict__ filtH,
        float2* __restrict__ Z, int chOff, int nTiles) {
    constexpr int W = N/2 + 1;
    __shared__ float2 lds[2][CB*N];
    __shared__ float2 tw[N];
    int tid = threadIdx.x, bid = blockIdx.x, y = blockIdx.y;
    int i = bid / nTiles, v0 = (bid % nTiles) * CB;
    fill_tw<N,true>(tw, tid);
    const float2* spec = (y == 0) ? specA : specB;
    const float* filt = nullptr;
    if (MODE >= 1) filt = (y == 0) ? filtA : filtB + (size_t)(y - chOff) * filtStride;
    const float2* base = spec + (size_t)i * N * W;
    float2* Zb = Z + ((size_t)y * 24 + i) * N * W;
    for (int q = tid; q < CB*N; q += 256) {
        int c = q % CB, r = q / CB, v = v0 + c;
        float2 val = make_float2(0.f, 0.f);
        if (v < W) {
            val = base[(size_t)r*W + v];
            if (MODE >= 1) {
                int fi = ((r + N/2) & (N-1)) * W + v;
                float f = filt[fi];
                if (MODE == 2 && y > 0) f *= filtH[fi];
                val.x *= f; val.y *= f;
            }
        }
        lds[0][c*N + r] = val;
    }
    float2* res = fft_lds<N, CB, true>(&lds[0][0], &lds[1][0], tw, tid);
    for (int q = tid; q < CB*N; q += 256) {
        int c = q % CB, r = q / CB, v = v0 + c;
        if (v < W) Zb[(size_t)r*W + v] = res[c*N + r];
    }
}

// Row-wise irfft (numpy: imag of DC & Nyquist dropped), scale 1/N^2.
// gridDim.y selects Z slot + output channel.
template<int N, int RB>
__global__ __launch_bounds__(256) void k_irfft_rows(
        const float2* __restrict__ Z,
        float* __restrict__ outA, int CHA,
        float* __restrict__ outB, int CHB, int chOff, int rowBlocks) {
    constexpr int W = N/2 + 1;
    __shared__ float2 lds[2][RB*N];
    __shared__ float2 tw[N];
    int tid = threadIdx.x, bid = blockIdx.x, y = blockIdx.y;
    int i = bid / rowBlocks, u0 = (bid % rowBlocks) * RB;
    fill_tw<N,true>(tw, tid);
    const float2* Zb = Z + ((size_t)y * 24 + i) * N * W;
    float* outb; int CH, ch;
    if (y == 0) { outb = outA; CH = CHA; ch = 0; }
    else        { outb = outB; CH = CHB; ch = y - chOff; }
    for (int q = tid; q < RB*N; q += 256) {
        int f = q / N, p = q % N;
        const float2* Zr = Zb + (size_t)(u0 + f) * W;
        float2 val;
        if (p == 0)          { float2 t = Zr[0];     val = make_float2(t.x, 0.f); }
        else if (p < N/2)    { val = Zr[p]; }
        else if (p == N/2)   { float2 t = Zr[N/2];   val = make_float2(t.x, 0.f); }
        else                 { float2 t = Zr[N - p]; val = make_float2(t.x, -t.y); }
        lds[0][f*N + p] = val;
    }
    float2* res = fft_lds<N, RB, true>(&lds[0][0], &lds[1][0], tw, tid);
    constexpr float sc = 1.0f / ((float)N * (float)N);
    for (int q = tid; q < RB*N; q += 256) {
        int f = q / N, p = q % N;
        int u = u0 + f;
        outb[(((size_t)i * CH + ch) * N + u) * N + p] = res[f*N + p].x * sc;
    }
}

extern "C" void kernel_launch(void* const* d_in, const int* in_sizes, int n_in,
                              void* d_out, int out_size, void* d_ws, size_t ws_size,
                              hipStream_t stream) {
    auto find = [&](int sz) -> const float* {
        for (int t = 0; t < n_in; ++t)
            if (in_sizes[t] == sz) return (const float*)d_in[t];
        return nullptr;
    };
    const float* x   = find(6291456);   // (8,3,512,512)
    const float* hl0 = find(263168);    // (2,512,257)
    const float* b0f = find(526336);    // (4,512,257)
    const float* l0f = find(33024);     // (1,256,129)
    const float* b1f = find(132096);    // (4,256,129)
    const float* l1f = find(8320);      // (1,128,65)
    const float* b2f = find(33280);     // (4,128,65)
    const float* l2f = find(2112);      // (1,64,33)
    const float* b3f = find(8448);      // (4,64,33)
    const float* l3f = find(544);       // (1,32,17)
    float* out = (float*)d_out;
    if (!x || !hl0 || !b0f || !l0f || !b1f || !l1f || !b2f || !l2f || !b3f || !l3f) return;

    const size_t P0 = (size_t)512*257, P1 = (size_t)256*129, P2 = (size_t)128*65,
                 P3 = (size_t)64*33,  P4 = (size_t)32*17;
    char* w = (char*)d_ws;
    float2* S   = (float2*)w; w += 24*P0*8;
    float2* LF1 = (float2*)w; w += 24*P1*8;
    float2* LF2 = (float2*)w; w += 24*P2*8;
    float2* LF3 = (float2*)w; w += 24*P3*8;
    float2* LF4 = (float2*)w; w += 24*P4*8;
    // Single Z arena, reused by every level (stream-serialized): sized for level 0.
    float2* Zar = (float2*)w; w += 5*24*P0*8;
    if ((size_t)(w - (char*)d_ws) > ws_size) return;  // ~160.2 MB needed

    const float* hl0_hi = hl0 + 512*257;   // channel 1 (lowpass)

    // Forward rfft2
    k_fwd_rows<<<dim3(24*128), 256, 0, stream>>>(x, S);
    k_fwd_cols<512,4><<<dim3(24*65), 256, 0, stream>>>(S, 65);

    // LF1..LF4 in one pass (composed gathers from S)
    k_lfall<<<dim3(4125), 256, 0, stream>>>(S, hl0, l0f, l1f, l2f, l3f, LF1, LF2, LF3, LF4);

    // Level 0: y=0 -> h0 (hl0 ch0 * S); y=1..4 -> b0[k] = b0f[k]*hl0_hi*S
    k_inv_cols<512,4,2><<<dim3(24*65, 5), 256, 0, stream>>>(S, S, hl0, b0f, (int)P0, hl0_hi, Zar, 1, 65);
    k_irfft_rows<512,4><<<dim3(24*128, 5), 256, 0, stream>>>(Zar, out + 0, 1, out + 6291456, 4, 1, 128);

    // Level 1
    k_inv_cols<256,8,1><<<dim3(24*17, 4), 256, 0, stream>>>(LF1, LF1, b1f, b1f, (int)P1, nullptr, Zar, 0, 17);
    k_irfft_rows<256,8><<<dim3(24*32, 4), 256, 0, stream>>>(Zar, out + 31457280, 4, out + 31457280, 4, 0, 32);

    // Level 2
    k_inv_cols<128,16,1><<<dim3(24*5, 4), 256, 0, stream>>>(LF2, LF2, b2f, b2f, (int)P2, nullptr, Zar, 0, 5);
    k_irfft_rows<128,16><<<dim3(24*8, 4), 256, 0, stream>>>(Zar, out + 37748736, 4, out + 37748736, 4, 0, 8);

    // Level 3
    k_inv_cols<64,32,1><<<dim3(24*2, 4), 256, 0, stream>>>(LF3, LF3, b3f, b3f, (int)P3, nullptr, Zar, 0, 2);
    k_irfft_rows<64,32><<<dim3(24*2, 4), 256, 0, stream>>>(Zar, out + 39321600, 4, out + 39321600, 4, 0, 2);

    // Level 4 (final lowpass)
    k_inv_cols<32,64,0><<<dim3(24*1, 1), 256, 0, stream>>>(LF4, LF4, nullptr, nullptr, 0, nullptr, Zar, 0, 1);
    k_irfft_rows<32,32><<<dim3(24*1, 1), 256, 0, stream>>>(Zar, out + 39714816, 1, out + 39714816, 1, 0, 1);

    (void)out_size; (void)ws_size;
}

// Round 6
// 490.862 us; speedup vs baseline: 1.6405x; 1.2343x over previous
//
#include <hip/hip_runtime.h>
#include <hip/hip_bf16.h>

// Steerable pyramid via single-buffer register Stockham LDS FFTs.
// Spectra stored (image, u, v) float2 with PADDED row stride WP = N/2+16
// (128B-aligned rows -> fully-coalesced 64B sectors for 8-wide column tiles).
// LDS uses p + (p>>4) padding to break Stockham bank conflicts.
// fftshift folded into filter indexing: filt[(u + N/2) & (N-1)] (dense W stride).

#define PI_F 3.14159265358979323846f

static __device__ inline float2 f2add(float2 a, float2 b){ return make_float2(a.x+b.x, a.y+b.y); }
static __device__ inline float2 f2sub(float2 a, float2 b){ return make_float2(a.x-b.x, a.y-b.y); }
static __device__ inline float2 cmul(float2 a, float2 b){ return make_float2(a.x*b.x - a.y*b.y, a.x*b.y + a.y*b.x); }

#define PIDX(p) ((p) + ((p) >> 4))

template<int N, bool INV>
static __device__ inline void fill_tw(float2* tw, int tid) {
    for (int m = tid; m < N; m += 256) {
        float ang = (INV ? 2.0f * PI_F : -2.0f * PI_F) * (float)m / (float)N;
        float s, c; __sincosf(ang, &s, &c);
        tw[m] = make_float2(c, s);
    }
}

// In-place single-LDS-buffer mixed radix-4/2 Stockham. F FFTs of length N.
// Element (f,p) lives at buf[f*STR + PIDX(p)], STR = N + N/16 + 1.
// Pattern per stage: barrier; read all inputs to regs; barrier; write outputs.
template<int N, int F, bool INV>
static __device__ void fft_reg(float2* __restrict__ buf, const float2* __restrict__ tw, int tid) {
    constexpr int L = (N==512)?9:(N==256)?8:(N==128)?7:(N==64)?6:5;
    constexpr int STR = N + (N>>4) + 1;
    if constexpr (L & 1) {      // radix-2 first stage (w == 1)
        constexpr int NB2 = F*(N/2);
        constexpr int PT2 = (NB2 + 255)/256;
        constexpr bool G2 = (NB2 % 256) != 0;
        float2 ra[PT2], rb[PT2];
        __syncthreads();
#pragma unroll
        for (int t = 0; t < PT2; ++t) {
            int q = t*256 + tid;
            if (!G2 || q < NB2) {
                int f = q / (N/2), j = q % (N/2);
                ra[t] = buf[f*STR + PIDX(j)];
                rb[t] = buf[f*STR + PIDX(j + N/2)];
            }
        }
        __syncthreads();
#pragma unroll
        for (int t = 0; t < PT2; ++t) {
            int q = t*256 + tid;
            if (!G2 || q < NB2) {
                int f = q / (N/2), j = q % (N/2);
                buf[f*STR + PIDX(2*j)]   = f2add(ra[t], rb[t]);
                buf[f*STR + PIDX(2*j+1)] = f2sub(ra[t], rb[t]);
            }
        }
    }
    constexpr int S4  = L/2;
    constexpr int NB4 = F*(N/4);
    constexpr int PT4 = (NB4 + 255)/256;
    constexpr bool G4 = (NB4 % 256) != 0;
#pragma unroll
    for (int s = 0; s < S4; ++s) {
        const int Ns = ((L & 1) ? 2 : 1) << (2*s);
        float2 c0[PT4], c1[PT4], c2[PT4], c3[PT4];
        __syncthreads();
#pragma unroll
        for (int t = 0; t < PT4; ++t) {
            int q = t*256 + tid;
            if (!G4 || q < NB4) {
                int f = q / (N/4), j = q % (N/4);
                float2* b = buf + f*STR;
                c0[t] = b[PIDX(j)];
                c1[t] = b[PIDX(j + (N/4))];
                c2[t] = b[PIDX(j + 2*(N/4))];
                c3[t] = b[PIDX(j + 3*(N/4))];
            }
        }
        __syncthreads();
#pragma unroll
        for (int t = 0; t < PT4; ++t) {
            int q = t*256 + tid;
            if (!G4 || q < NB4) {
                int f = q / (N/4), j = q % (N/4);
                int r = j & (Ns - 1);
                int m = r * (N / (4*Ns));
                float2 w1 = tw[m];
                float2 w2 = tw[(2*m) & (N-1)];
                float2 w3 = tw[(3*m) & (N-1)];
                float2 d0 = c0[t];
                float2 d1 = cmul(w1, c1[t]);
                float2 d2 = cmul(w2, c2[t]);
                float2 d3 = cmul(w3, c3[t]);
                float2 t0 = f2add(d0, d2), t1 = f2sub(d0, d2);
                float2 t2 = f2add(d1, d3), dd = f2sub(d1, d3);
                float2 t3 = INV ? make_float2(-dd.y, dd.x) : make_float2(dd.y, -dd.x);
                float2* b = buf + f*STR;
                int d = ((j - r) << 2) | r;
                b[PIDX(d)]        = f2add(t0, t2);
                b[PIDX(d + Ns)]   = f2add(t1, t3);
                b[PIDX(d + 2*Ns)] = f2sub(t0, t2);
                b[PIDX(d + 3*Ns)] = f2sub(t1, t3);
            }
        }
    }
    __syncthreads();
}

// Forward row rfft: 2 packed FFTs per block (4 real rows). Writes S (WP=272).
__global__ __launch_bounds__(256) void k_fwd_rows(const float* __restrict__ x,
                                                  float2* __restrict__ S) {
    constexpr int STR = 512 + 32 + 1;
    __shared__ float2 buf[2*STR];
    __shared__ float2 tw[512];
    int bid = blockIdx.x;
    int i = bid / 128, p = bid % 128;
    int y0 = 4*p;
    const float* rbase = x + ((size_t)(i*512 + y0)) * 512;
    int tid = threadIdx.x;
    fill_tw<512,false>(tw, tid);
    for (int t = tid; t < 1024; t += 256) {
        int f = t >> 9, idx = t & 511;
        buf[f*STR + PIDX(idx)] = make_float2(rbase[(size_t)(2*f)*512 + idx],
                                             rbase[(size_t)(2*f+1)*512 + idx]);
    }
    fft_reg<512,2,false>(buf, tw, tid);
    for (int t = tid; t < 2*257; t += 256) {
        int f = t / 257, v = t % 257;
        float2 Zv = buf[f*STR + PIDX(v)];
        float2 Zc = buf[f*STR + PIDX((512 - v) & 511)];
        float2* SA = S + ((size_t)(i*512 + y0 + 2*f)) * 272;
        SA[v]       = make_float2(0.5f*(Zv.x + Zc.x), 0.5f*(Zv.y - Zc.y));
        SA[272 + v] = make_float2(0.5f*(Zv.y + Zc.y), 0.5f*(Zc.x - Zv.x));
    }
}

// Forward column FFT, in place on S (padded WP), 8 columns per block.
template<int N>
__global__ __launch_bounds__(256) void k_fwd_cols(float2* __restrict__ S, int nTiles) {
    constexpr int W = N/2 + 1, WP = N/2 + 16;
    constexpr int STR = N + (N>>4) + 1;
    __shared__ float2 buf[8*STR];
    __shared__ float2 tw[N];
    int tid = threadIdx.x, bid = blockIdx.x;
    int i = bid / nTiles, v0 = (bid % nTiles) * 8;
    fill_tw<N,false>(tw, tid);
    float2* base = S + (size_t)i * N * WP;
    for (int q = tid; q < 8*N; q += 256) {
        int c = q & 7, r = q >> 3, v = v0 + c;
        buf[c*STR + PIDX(r)] = (v < W) ? base[(size_t)r*WP + v] : make_float2(0.f,0.f);
    }
    fft_reg<N,8,false>(buf, tw, tid);
    for (int q = tid; q < 8*N; q += 256) {
        int c = q & 7, r = q >> 3, v = v0 + c;
        if (v < W) base[(size_t)r*WP + v] = buf[c*STR + PIDX(r)];
    }
}

// LF1..LF4 directly from S: composed crop-gathers x product of filter taps.
__global__ void k_lfall(const float2* __restrict__ S, const float* __restrict__ hl0,
                        const float* __restrict__ l0, const float* __restrict__ l1,
                        const float* __restrict__ l2, const float* __restrict__ l3,
                        float2* __restrict__ LF1, float2* __restrict__ LF2,
                        float2* __restrict__ LF3, float2* __restrict__ LF4) {
    const int D1 = 256*129, D2 = 128*65, D3 = 64*33, D4 = 32*17;
    const int T1 = 24*D1, T2 = 24*D2, T3 = 24*D3, T4 = 24*D4;
    int idx = blockIdx.x * 256 + threadIdx.x;
    int lev, rem; float2* dst; int Wnp;
    if (idx < T1)               { lev=1; rem=idx;          dst=LF1; Wnp=144; }
    else if (idx < T1+T2)       { lev=2; rem=idx-T1;       dst=LF2; Wnp=80; }
    else if (idx < T1+T2+T3)    { lev=3; rem=idx-T1-T2;    dst=LF3; Wnp=48; }
    else if (idx < T1+T2+T3+T4) { lev=4; rem=idx-T1-T2-T3; dst=LF4; Wnp=32; }
    else return;
    int Hn = 512 >> lev, Wn = Hn/2 + 1;
    int dper = Hn * Wn;
    int i = rem / dper, off = rem % dper;
    int uo = off / Wn, v = off % Wn;
    int u = uo;
    float f = 1.0f;
    for (int m = lev - 1; m >= 0; --m) {
        int Hc = 512 >> (m + 1);
        int Wc = Hc/2 + 1;
        int s2 = (u + Hc/2) & (Hc - 1);
        const float* ls = (m==0) ? l0 : (m==1) ? l1 : (m==2) ? l2 : l3;
        f *= ls[s2 * Wc + v];
        int Hp = 512 >> m;
        u = (3*(Hp/4) + s2) & (Hp - 1);
    }
    f *= hl0[512*257 + (((u + 256) & 511) * 257 + v)];
    float2 sv = S[((size_t)i * 512 + u) * 272 + v];
    dst[((size_t)i * Hn + uo) * Wnp + v] = make_float2(sv.x * f, sv.y * f);
}

// Inverse column FFT + filter multiply. 8 cols/block; gridDim.y = batch slice.
// MODE: 0 none; 1 filt = filtB[(y+yBase)*stride]; 2 (level0): eff==0 -> filtA,
// else filtB[eff-1]*filtH.
template<int N, int MODE>
__global__ __launch_bounds__(256) void k_inv_cols(
        const float2* __restrict__ spec,
        const float* __restrict__ filtA, const float* __restrict__ filtB,
        const float* __restrict__ filtH, int filtStride, int yBase,
        float2* __restrict__ Z, int nTiles) {
    constexpr int W = N/2 + 1, WP = N/2 + 16;
    constexpr int STR = N + (N>>4) + 1;
    __shared__ float2 buf[8*STR];
    __shared__ float2 tw[N];
    int tid = threadIdx.x, bid = blockIdx.x, y = blockIdx.y;
    int i = bid / nTiles, v0 = (bid % nTiles) * 8;
    int eff = y + yBase;
    fill_tw<N,true>(tw, tid);
    const float* filt = nullptr;
    bool useH = false;
    if (MODE == 1) filt = filtB + (size_t)eff * filtStride;
    if (MODE == 2) {
        if (eff == 0) filt = filtA;
        else { filt = filtB + (size_t)(eff - 1) * filtStride; useH = true; }
    }
    const float2* base = spec + (size_t)i * N * WP;
    float2* Zb = Z + ((size_t)y * 24 + i) * N * WP;
    for (int q = tid; q < 8*N; q += 256) {
        int c = q & 7, r = q >> 3, v = v0 + c;
        float2 val = make_float2(0.f, 0.f);
        if (v < W) {
            val = base[(size_t)r*WP + v];
            if (MODE >= 1) {
                int fi = ((r + N/2) & (N-1)) * W + v;
                float f = filt[fi];
                if (MODE == 2 && useH) f *= filtH[fi];
                val.x *= f; val.y *= f;
            }
        }
        buf[c*STR + PIDX(r)] = val;
    }
    fft_reg<N,8,true>(buf, tw, tid);
    for (int q = tid; q < 8*N; q += 256) {
        int c = q & 7, r = q >> 3, v = v0 + c;
        if (v < W) Zb[(size_t)r*WP + v] = buf[c*STR + PIDX(r)];
    }
}

// Row-wise irfft (numpy: imag of DC & Nyquist dropped), scale 1/N^2.
template<int N, int RB>
__global__ __launch_bounds__(256) void k_irfft_rows(
        const float2* __restrict__ Z,
        float* __restrict__ outA, int CHA,
        float* __restrict__ outB, int CHB,
        int chOff, int yBase, int rowBlocks) {
    constexpr int WP = N/2 + 16;
    constexpr int STR = N + (N>>4) + 1;
    __shared__ float2 buf[RB*STR];
    __shared__ float2 tw[N];
    int tid = threadIdx.x, bid = blockIdx.x, y = blockIdx.y;
    int i = bid / rowBlocks, u0 = (bid % rowBlocks) * RB;
    int eff = y + yBase;
    fill_tw<N,true>(tw, tid);
    const float2* Zb = Z + ((size_t)y * 24 + i) * N * WP;
    float* outb; int CH, ch;
    if (eff == 0) { outb = outA; CH = CHA; ch = 0; }
    else          { outb = outB; CH = CHB; ch = eff - chOff; }
    for (int q = tid; q < RB*N; q += 256) {
        int f = q / N, p = q % N;
        const float2* Zr = Zb + (size_t)(u0 + f) * WP;
        float2 val;
        if (p == 0)          { float2 t = Zr[0];     val = make_float2(t.x, 0.f); }
        else if (p < N/2)    { val = Zr[p]; }
        else if (p == N/2)   { float2 t = Zr[N/2];   val = make_float2(t.x, 0.f); }
        else                 { float2 t = Zr[N - p]; val = make_float2(t.x, -t.y); }
        buf[f*STR + PIDX(p)] = val;
    }
    fft_reg<N,RB,true>(buf, tw, tid);
    constexpr float sc = 1.0f / ((float)N * (float)N);
    for (int q = tid; q < RB*N; q += 256) {
        int f = q / N, p = q % N;
        outb[(((size_t)i * CH + ch) * N + (u0 + f)) * N + p] = buf[f*STR + PIDX(p)].x * sc;
    }
}

extern "C" void kernel_launch(void* const* d_in, const int* in_sizes, int n_in,
                              void* d_out, int out_size, void* d_ws, size_t ws_size,
                              hipStream_t stream) {
    auto find = [&](int sz) -> const float* {
        for (int t = 0; t < n_in; ++t)
            if (in_sizes[t] == sz) return (const float*)d_in[t];
        return nullptr;
    };
    const float* x   = find(6291456);   // (8,3,512,512)
    const float* hl0 = find(263168);    // (2,512,257)
    const float* b0f = find(526336);    // (4,512,257)
    const float* l0f = find(33024);     // (1,256,129)
    const float* b1f = find(132096);    // (4,256,129)
    const float* l1f = find(8320);      // (1,128,65)
    const float* b2f = find(33280);     // (4,128,65)
    const float* l2f = find(2112);      // (1,64,33)
    const float* b3f = find(8448);      // (4,64,33)
    const float* l3f = find(544);       // (1,32,17)
    float* out = (float*)d_out;
    if (!x || !hl0 || !b0f || !l0f || !b1f || !l1f || !b2f || !l2f || !b3f || !l3f) return;

    // Padded per-image spectrum sizes (float2 elements)
    const size_t P0p = (size_t)512*272, P1p = (size_t)256*144, P2p = (size_t)128*80,
                 P3p = (size_t)64*48,  P4p = (size_t)32*32;
    char* w = (char*)d_ws;
    float2* S   = (float2*)w; w += 24*P0p*8;
    float2* LF1 = (float2*)w; w += 24*P1p*8;
    float2* LF2 = (float2*)w; w += 24*P2p*8;
    float2* LF3 = (float2*)w; w += 24*P3p*8;
    float2* LF4 = (float2*)w; w += 24*P4p*8;
    float2* Zar = (float2*)w; w += 3*24*P0p*8;   // 3 level-0 slices; reused by all levels
    if ((size_t)(w - (char*)d_ws) > ws_size) return;  // ~111.4 MiB needed

    const float* hl0_hi = hl0 + 512*257;   // channel 1 (lowpass)

    // Forward rfft2
    k_fwd_rows<<<dim3(24*128), 256, 0, stream>>>(x, S);
    k_fwd_cols<512><<<dim3(24*33), 256, 0, stream>>>(S, 33);

    // LF1..LF4 in one pass
    k_lfall<<<dim3(4125), 256, 0, stream>>>(S, hl0, l0f, l1f, l2f, l3f, LF1, LF2, LF3, LF4);

    // Level 0, batch A (eff 0..2: h0, b0[0], b0[1])
    k_inv_cols<512,2><<<dim3(24*33, 3), 256, 0, stream>>>(S, hl0, b0f, hl0_hi, 512*257, 0, Zar, 33);
    k_irfft_rows<512,4><<<dim3(24*128, 3), 256, 0, stream>>>(Zar, out, 1, out + 6291456, 4, 1, 0, 128);
    // Level 0, batch B (eff 3..4: b0[2], b0[3])
    k_inv_cols<512,2><<<dim3(24*33, 2), 256, 0, stream>>>(S, hl0, b0f, hl0_hi, 512*257, 3, Zar, 33);
    k_irfft_rows<512,4><<<dim3(24*128, 2), 256, 0, stream>>>(Zar, out, 1, out + 6291456, 4, 1, 3, 128);

    // Level 1
    k_inv_cols<256,1><<<dim3(24*17, 4), 256, 0, stream>>>(LF1, nullptr, b1f, nullptr, 256*129, 0, Zar, 17);
    k_irfft_rows<256,8><<<dim3(24*32, 4), 256, 0, stream>>>(Zar, out + 31457280, 4, out + 31457280, 4, 0, 0, 32);

    // Level 2
    k_inv_cols<128,1><<<dim3(24*9, 4), 256, 0, stream>>>(LF2, nullptr, b2f, nullptr, 128*65, 0, Zar, 9);
    k_irfft_rows<128,16><<<dim3(24*8, 4), 256, 0, stream>>>(Zar, out + 37748736, 4, out + 37748736, 4, 0, 0, 8);

    // Level 3
    k_inv_cols<64,1><<<dim3(24*5, 4), 256, 0, stream>>>(LF3, nullptr, b3f, nullptr, 64*33, 0, Zar, 5);
    k_irfft_rows<64,32><<<dim3(24*2, 4), 256, 0, stream>>>(Zar, out + 39321600, 4, out + 39321600, 4, 0, 0, 2);

    // Level 4 (final lowpass)
    k_inv_cols<32,0><<<dim3(24*3, 1), 256, 0, stream>>>(LF4, nullptr, nullptr, nullptr, 0, 0, Zar, 3);
    k_irfft_rows<32,32><<<dim3(24, 1), 256, 0, stream>>>(Zar, out + 39714816, 1, out + 39714816, 1, 0, 0, 1);

    (void)out_size; (void)ws_size;
}